// Round 1
// 2174.296 us; speedup vs baseline: 1.4508x; 1.4508x over previous
//
#include <hip/hip_runtime.h>

#define T_ 4096
#define H_ 2048
#define E_ 64
#define F_ 768
#define K_ 8
#define C_ 1024
#define GRP 16

typedef unsigned short u16;
typedef __attribute__((ext_vector_type(8))) short bf16x8;          // 8 bf16 (4 VGPRs)
typedef __attribute__((ext_vector_type(8))) unsigned short u16x8;  // 16B store unit
typedef __attribute__((ext_vector_type(4))) float f32x4;

typedef __attribute__((address_space(1))) const void gvoid;
typedef __attribute__((address_space(3))) void lvoid;

__device__ __forceinline__ void gload16(const u16* g, u16* l) {
  __builtin_amdgcn_global_load_lds((gvoid*)g, (lvoid*)l, 16, 0, 0);
}

__device__ __forceinline__ u16 f2b(float f) {
  unsigned u = __builtin_bit_cast(unsigned, f);
  u += 0x7fffu + ((u >> 16) & 1u);   // RNE
  return (u16)(u >> 16);
}

// ---------------- x -> bf16 ----------------
__global__ __launch_bounds__(256) void cvt_x_kernel(const float* __restrict__ x, u16* __restrict__ xb) {
  int i = blockIdx.x * 256 + threadIdx.x;
  float4 v = ((const float4*)x)[i];
  ushort4 o;
  o.x = f2b(v.x); o.y = f2b(v.y); o.z = f2b(v.z); o.w = f2b(v.w);
  ((ushort4*)xb)[i] = o;
}

// ---------------- weight fp32 [e][R][CC] -> bf16 transposed [z][CC][R] ----------------
// 64x64 tiles via LDS; reads/writes fully coalesced (128B/8-lane group)
template <int R, int CC>
__global__ __launch_bounds__(256) void cvt_t_kernel(const float* __restrict__ in, u16* __restrict__ out, int e0) {
  __shared__ u16 s[64][72];   // [in-col][in-row], stride 144B keeps 16B-aligned reads
  const float* ip = in + ((size_t)(e0 + blockIdx.z) * R + blockIdx.y * 64) * CC + blockIdx.x * 64;
  u16* op = out + ((size_t)blockIdx.z * CC + blockIdx.x * 64) * R + blockIdx.y * 64;
  int tid = threadIdx.x;
#pragma unroll
  for (int j = 0; j < 4; ++j) {
    int idx = j * 256 + tid;
    int r = idx >> 4, c4 = (idx & 15) * 4;
    float4 v = *(const float4*)(ip + (size_t)r * CC + c4);
    s[c4 + 0][r] = f2b(v.x);
    s[c4 + 1][r] = f2b(v.y);
    s[c4 + 2][r] = f2b(v.z);
    s[c4 + 3][r] = f2b(v.w);
  }
  __syncthreads();
#pragma unroll
  for (int j = 0; j < 2; ++j) {
    int idx = j * 256 + tid;
    int c = idx >> 3, seg = (idx & 7) * 8;
    u16x8 v = *(const u16x8*)&s[c][seg];
    *(u16x8*)(op + (size_t)c * R + seg) = v;
  }
}

// ---------------- router: fp32 logits, top-8, renormalized softmax weights ----------------
__global__ __launch_bounds__(256) void router_kernel(const float* __restrict__ x, const float* __restrict__ gw,
                                                     int* __restrict__ topi, float* __restrict__ topw) {
  __shared__ float xs[4][H_];
  __shared__ float lg[4][E_];
  int t0 = blockIdx.x * 4;
  const float4* xsrc = (const float4*)(x + (size_t)t0 * H_);
  float4* xdst = (float4*)&xs[0][0];
#pragma unroll
  for (int j = 0; j < 8; ++j) xdst[j * 256 + threadIdx.x] = xsrc[j * 256 + threadIdx.x];
  __syncthreads();
  int e  = threadIdx.x & 63;
  int tt = threadIdx.x >> 6;
  const float4* g4 = (const float4*)(gw + (size_t)e * H_);
  const float4* x4 = (const float4*)&xs[tt][0];
  float a0 = 0.f, a1 = 0.f, a2 = 0.f, a3 = 0.f;
  for (int i = 0; i < H_ / 4; ++i) {
    float4 g = g4[i]; float4 xv = x4[i];
    a0 += g.x * xv.x; a1 += g.y * xv.y; a2 += g.z * xv.z; a3 += g.w * xv.w;
  }
  lg[tt][e] = (a0 + a1) + (a2 + a3);
  __syncthreads();
  int wave = threadIdx.x >> 6;
  int lane = threadIdx.x & 63;
  int t = t0 + wave;
  float v = lg[wave][lane];
  float m = 0.f, s = 0.f, myw = 0.f;
  int myi = 0;
#pragma unroll
  for (int k = 0; k < 8; ++k) {
    float bv = v; int bi = lane;
#pragma unroll
    for (int off = 32; off > 0; off >>= 1) {
      float ov = __shfl_down(bv, off);
      int   oi = __shfl_down(bi, off);
      if (ov > bv || (ov == bv && oi < bi)) { bv = ov; bi = oi; }
    }
    bv = __shfl(bv, 0); bi = __shfl(bi, 0);
    if (k == 0) m = bv;
    float ev = expf(bv - m);
    s += ev;
    if (lane == k) { myi = bi; myw = ev; }
    if (lane == bi) v = -__builtin_inff();
  }
  if (lane < 8) {
    topi[t * K_ + lane] = myi;
    topw[t * K_ + lane] = myw / s;
  }
}

// ---------------- dispatch: slot assignment ----------------
__global__ __launch_bounds__(256) void dispatch_kernel(const int* __restrict__ topi, int* __restrict__ counts,
                                                       int* __restrict__ posv, int* __restrict__ perm) {
  int i = blockIdx.x * 256 + threadIdx.x;
  int e = topi[i];
  int p = atomicAdd(&counts[e], 1);
  posv[i] = p;
  if (p < C_) perm[e * C_ + p] = i >> 3;   // token index
}

// ---------------- GEMM1: act[rows,768] = silu(Xg)*Xu ----------------
// m97 structure: 128x128 tile (64 gate + 64 up cols), BK=64, global_load_lds w/ source-swizzle
__global__ __launch_bounds__(256, 3) void gemm1_kernel(const u16* __restrict__ xb, const u16* __restrict__ wt,
                                                       const int* __restrict__ perm, const int* __restrict__ counts,
                                                       u16* __restrict__ act, int e0) {
  __shared__ __align__(16) u16 sh[2 * 128 * 64];
  u16* As = sh;
  u16* Bs = sh + 128 * 64;
  int ez = blockIdx.z, e = e0 + ez;
  int rb = blockIdx.y, nb = blockIdx.x;
  int count = counts[e]; if (count > C_) count = C_;
  if (rb * 128 >= count) return;
  int tid = threadIdx.x, lane = tid & 63, wave = tid >> 6;
  const u16 *asrc[4], *bsrc[4];
  {
    int u = tid & 7, rr = tid >> 3;
#pragma unroll
    for (int i = 0; i < 4; ++i) {
      int row = i * 32 + rr;
      int us = (u ^ (row & 7)) * 8;          // pre-swizzled global source (rule #21)
      int gr = rb * 128 + row; if (gr > count - 1) gr = count - 1;   // clamp: dup last token, rows>=count never combined
      asrc[i] = xb + (size_t)perm[e * C_ + gr] * H_ + us;
      int grow = nb * 64 + row + ((row >= 64) ? 704 : 0);            // gate cols then up cols (+768-64)
      bsrc[i] = wt + ((size_t)ez * 1536 + grow) * H_ + us;
    }
  }
  int fl = lane & 15, quad = lane >> 4, m0 = wave * 32;
  f32x4 acc[2][8];
#pragma unroll
  for (int a = 0; a < 2; ++a)
#pragma unroll
    for (int b = 0; b < 8; ++b) acc[a][b] = (f32x4){0.f, 0.f, 0.f, 0.f};

  for (int kt = 0; kt < H_ / 64; ++kt) {
    __syncthreads();   // prev tile's ds_reads done
#pragma unroll
    for (int i = 0; i < 4; ++i) gload16(asrc[i] + kt * 64, As + (i * 4 + wave) * 512);
#pragma unroll
    for (int i = 0; i < 4; ++i) gload16(bsrc[i] + kt * 64, Bs + (i * 4 + wave) * 512);
    __syncthreads();   // vmcnt(0) drain -> tiles ready
#pragma unroll
    for (int kb = 0; kb < 2; ++kb) {
      int sA = ((kb * 4 + quad) ^ (fl & 7)) * 8;   // un-swizzle on read; 2-way banks (free)
      bf16x8 a0 = *(const bf16x8*)&As[(m0 + fl) * 64 + sA];
      bf16x8 a1 = *(const bf16x8*)&As[(m0 + 16 + fl) * 64 + sA];
#pragma unroll
      for (int nf = 0; nf < 8; ++nf) {
        bf16x8 bfr = *(const bf16x8*)&Bs[(nf * 16 + fl) * 64 + sA];
        acc[0][nf] = __builtin_amdgcn_mfma_f32_16x16x32_bf16(a0, bfr, acc[0][nf], 0, 0, 0);
        acc[1][nf] = __builtin_amdgcn_mfma_f32_16x16x32_bf16(a1, bfr, acc[1][nf], 0, 0, 0);
      }
    }
  }
  // epilogue: SwiGLU -> LDS tile (quad-XOR swizzle) -> coalesced 16B/lane stores
  __syncthreads();
#pragma unroll
  for (int mf = 0; mf < 2; ++mf)
#pragma unroll
    for (int nf = 0; nf < 4; ++nf)
#pragma unroll
      for (int rg = 0; rg < 4; ++rg) {
        float g = acc[mf][nf][rg];
        float uu = acc[mf][nf + 4][rg];
        float a = (g / (1.f + __expf(-g))) * uu;
        int row = m0 + mf * 16 + quad * 4 + rg;
        int col = (nf * 16 + fl) ^ (quad << 4);   // note (row>>2)&3 == quad
        sh[row * 64 + col] = f2b(a);
      }
  __syncthreads();
  size_t rowbase = (size_t)e * C_ + rb * 128;
#pragma unroll
  for (int i = 0; i < 4; ++i) {
    int li = i * 256 + tid;
    int r = li >> 3, j = li & 7;
    int cs = (j * 8) ^ (((r >> 2) & 3) << 4);
    u16x8 v = *(const u16x8*)&sh[r * 64 + cs];
    *(u16x8*)(act + (rowbase + r) * F_ + nb * 64 + j * 8) = v;
  }
}

// ---------------- GEMM2: ye[rows,2048] = act @ w_down^T ----------------
__global__ __launch_bounds__(256, 3) void gemm2_kernel(const u16* __restrict__ act, const u16* __restrict__ wt,
                                                       const int* __restrict__ counts, u16* __restrict__ ye, int e0) {
  __shared__ __align__(16) u16 sh[2 * 128 * 64];
  u16* As = sh;
  u16* Bs = sh + 128 * 64;
  int ez = blockIdx.z, e = e0 + ez;
  int rb = blockIdx.y, nb = blockIdx.x;
  int count = counts[e]; if (count > C_) count = C_;
  if (rb * 128 >= count) return;
  int tid = threadIdx.x, lane = tid & 63, wave = tid >> 6;
  const u16 *asrc[4], *bsrc[4];
  {
    int u = tid & 7, rr = tid >> 3;
#pragma unroll
    for (int i = 0; i < 4; ++i) {
      int row = i * 32 + rr;
      int us = (u ^ (row & 7)) * 8;
      asrc[i] = act + ((size_t)e * C_ + rb * 128 + row) * F_ + us;
      bsrc[i] = wt + ((size_t)ez * H_ + nb * 128 + row) * F_ + us;
    }
  }
  int fl = lane & 15, quad = lane >> 4, m0 = wave * 32;
  f32x4 acc[2][8];
#pragma unroll
  for (int a = 0; a < 2; ++a)
#pragma unroll
    for (int b = 0; b < 8; ++b) acc[a][b] = (f32x4){0.f, 0.f, 0.f, 0.f};

  for (int kt = 0; kt < F_ / 64; ++kt) {
    __syncthreads();
#pragma unroll
    for (int i = 0; i < 4; ++i) gload16(asrc[i] + kt * 64, As + (i * 4 + wave) * 512);
#pragma unroll
    for (int i = 0; i < 4; ++i) gload16(bsrc[i] + kt * 64, Bs + (i * 4 + wave) * 512);
    __syncthreads();
#pragma unroll
    for (int kb = 0; kb < 2; ++kb) {
      int sA = ((kb * 4 + quad) ^ (fl & 7)) * 8;
      bf16x8 a0 = *(const bf16x8*)&As[(m0 + fl) * 64 + sA];
      bf16x8 a1 = *(const bf16x8*)&As[(m0 + 16 + fl) * 64 + sA];
#pragma unroll
      for (int nf = 0; nf < 8; ++nf) {
        bf16x8 bfr = *(const bf16x8*)&Bs[(nf * 16 + fl) * 64 + sA];
        acc[0][nf] = __builtin_amdgcn_mfma_f32_16x16x32_bf16(a0, bfr, acc[0][nf], 0, 0, 0);
        acc[1][nf] = __builtin_amdgcn_mfma_f32_16x16x32_bf16(a1, bfr, acc[1][nf], 0, 0, 0);
      }
    }
  }
  // epilogue: 128x128 bf16 tile via LDS (fills all 32KB), coalesced stores
  __syncthreads();
#pragma unroll
  for (int mf = 0; mf < 2; ++mf)
#pragma unroll
    for (int nf = 0; nf < 8; ++nf)
#pragma unroll
      for (int rg = 0; rg < 4; ++rg) {
        int row = m0 + mf * 16 + quad * 4 + rg;
        int col = (nf * 16 + fl) ^ (quad << 4);
        sh[row * 128 + col] = f2b(acc[mf][nf][rg]);
      }
  __syncthreads();
  size_t rowbase = (size_t)e * C_ + rb * 128;
#pragma unroll
  for (int i = 0; i < 8; ++i) {
    int li = i * 256 + tid;
    int r = li >> 4, j = li & 15;
    int cs = (j * 8) ^ (((r >> 2) & 3) << 4);
    u16x8 v = *(const u16x8*)&sh[r * 128 + cs];
    *(u16x8*)(ye + (rowbase + r) * H_ + nb * 128 + j * 8) = v;
  }
}

// ---------------- combine: out[t] = sum_k w_k * ye[e_k, slot_k] ----------------
__global__ __launch_bounds__(256) void combine_kernel(const u16* __restrict__ ye, const int* __restrict__ topi,
                                                      const int* __restrict__ posv, const float* __restrict__ topw,
                                                      float* __restrict__ out) {
  int t = blockIdx.x, tid = threadIdx.x;
  __shared__ int se[8]; __shared__ int sp[8]; __shared__ float sw[8];
  if (tid < 8) { se[tid] = topi[t * 8 + tid]; sp[tid] = posv[t * 8 + tid]; sw[tid] = topw[t * 8 + tid]; }
  __syncthreads();
  int col = tid * 8;
  float acc[8];
#pragma unroll
  for (int j = 0; j < 8; ++j) acc[j] = 0.f;
#pragma unroll
  for (int k = 0; k < 8; ++k) {
    int p = sp[k];
    if (p >= C_) continue;
    uint4 v = *(const uint4*)(ye + ((size_t)se[k] * C_ + p) * H_ + col);
    float w = sw[k];
    unsigned arr[4] = {v.x, v.y, v.z, v.w};
#pragma unroll
    for (int j = 0; j < 4; ++j) {
      acc[2 * j]     += w * __builtin_bit_cast(float, arr[j] << 16);
      acc[2 * j + 1] += w * __builtin_bit_cast(float, arr[j] & 0xffff0000u);
    }
  }
  float4 o0 = {acc[0], acc[1], acc[2], acc[3]};
  float4 o1 = {acc[4], acc[5], acc[6], acc[7]};
  float* op = out + (size_t)t * H_ + col;
  *(float4*)op = o0;
  *(float4*)(op + 4) = o1;
}

extern "C" void kernel_launch(void* const* d_in, const int* in_sizes, int n_in,
                              void* d_out, int out_size, void* d_ws, size_t ws_size,
                              hipStream_t stream) {
  const float* x   = (const float*)d_in[0];
  const float* gw  = (const float*)d_in[1];
  const float* wgu = (const float*)d_in[2];
  const float* wd  = (const float*)d_in[3];
  float* out = (float*)d_out;

  char* w = (char*)d_ws;
  u16*  xb     = (u16*)(w + 0);              //  16,777,216
  int*  topi   = (int*)(w + 16777216);       //     131,072
  float* topw  = (float*)(w + 16908288);     //     131,072
  int*  posv   = (int*)(w + 17039360);       //     131,072
  int*  counts = (int*)(w + 17170432);       //       1,024 (pad)
  int*  perm   = (int*)(w + 17171456);       //     262,144
  u16*  act    = (u16*)(w + 17433600);       // 100,663,296  [E*C, F] bf16
  u16*  wb2    = (u16*)(w + 118096896);      //  50,331,648  bf16 w_down^T staging (16 experts)
  u16*  ye     = (u16*)(w + 168428544);      // 268,435,456  [E*C, H] bf16  (total ~436.9 MB)
  u16*  wb1    = ye;                          // wgu^T staging (100.7 MB) aliases ye; dead before gemm2 writes

  hipMemsetAsync(counts, 0, 64 * sizeof(int), stream);
  cvt_x_kernel<<<(T_ * H_ / 4) / 256, 256, 0, stream>>>(x, xb);
  router_kernel<<<T_ / 4, 256, 0, stream>>>(x, gw, topi, topw);
  dispatch_kernel<<<(T_ * K_) / 256, 256, 0, stream>>>(topi, counts, posv, perm);
  // chunked: convert 16 experts' weights (bf16, transposed) -> GEMM consumes them LLC-hot
  for (int g = 0; g < E_ / GRP; ++g) {
    cvt_t_kernel<H_, 2 * F_><<<dim3((2 * F_) / 64, H_ / 64, GRP), 256, 0, stream>>>(wgu, wb1, g * GRP);
    gemm1_kernel<<<dim3(12, 8, GRP), 256, 0, stream>>>(xb, wb1, perm, counts, act, g * GRP);
  }
  for (int g = 0; g < E_ / GRP; ++g) {
    cvt_t_kernel<F_, H_><<<dim3(H_ / 64, F_ / 64, GRP), 256, 0, stream>>>(wd, wb2, g * GRP);
    gemm2_kernel<<<dim3(16, 8, GRP), 256, 0, stream>>>(act, wb2, counts, ye, g * GRP);
  }
  combine_kernel<<<T_, 256, 0, stream>>>(ye, topi, posv, topw, out);
}